// Round 1
// baseline (959.330 us; speedup 1.0000x reference)
//
#include <hip/hip_runtime.h>

// Shapes: B=4, N1=N2=128, D=256, R=4, DH=D/2=128
// Pipeline:
//   A: h1p[b,r,i,e] = f1[b,i,:]@W1[r,:256,e] + b1[r,e];  h2[b,r,j,e] = f2[b,j,:]@W1[r,256:,e]
//   B: scores[b,r,i,j] = w3[r,:] . relu(W2[r]^T relu(h1p_i + h2_j) + b2[r]) + b3[r]
//   C: w = softmax_j(scores); all_rel[b,i,r*256+d] = sum_j w_ij f2[b,j,d]
//   D: out = relu(all_rel @ Wa1 + ba1) @ Wa2 + ba2

__global__ __launch_bounds__(256) void k_proj(
    const float* __restrict__ f1, const float* __restrict__ f2,
    const float* __restrict__ W1, const float* __restrict__ b1,
    float* __restrict__ h1p, float* __restrict__ h2)
{
  int bid = blockIdx.x;        // 256 blocks: half(2) x b(4) x r(4) x it(8)
  int half = bid >> 7;
  int rem  = bid & 127;
  int b  = rem >> 5;
  int r  = (rem >> 3) & 3;
  int it = rem & 7;
  int t = threadIdx.x;         // e = t (0..255)
  __shared__ float As[16][256];
  const float* f = half ? f2 : f1;
  for (int idx = t; idx < 16 * 256; idx += 256) {
    int ii = idx >> 8, d = idx & 255;
    As[ii][d] = f[(b * 128 + it * 16 + ii) * 256 + d];
  }
  __syncthreads();
  float acc[16];
  #pragma unroll
  for (int ii = 0; ii < 16; ++ii) acc[ii] = 0.f;
  const float* Wg = W1 + (r * 512 + (half ? 256 : 0)) * 256 + t;
  for (int d = 0; d < 256; ++d) {
    float wv = Wg[d * 256];
    #pragma unroll
    for (int ii = 0; ii < 16; ++ii)
      acc[ii] = fmaf(As[ii][d], wv, acc[ii]);
  }
  float bb = half ? 0.f : b1[r * 256 + t];
  float* ho = half ? h2 : h1p;
  #pragma unroll
  for (int ii = 0; ii < 16; ++ii)
    ho[((b * 4 + r) * 128 + it * 16 + ii) * 256 + t] = acc[ii] + bb;
}

// The 17.2 GFLOP kernel. Block = one (b,r) and a 16x16 (i,j) tile; thread = one pair.
// acc[128] register-resident (static indices via full unroll), W2 chunk in LDS read
// as float4 broadcast (all threads same address -> conflict-free).
__global__ __launch_bounds__(256, 2) void k_scores(
    const float* __restrict__ h1p, const float* __restrict__ h2,
    const float* __restrict__ W2, const float* __restrict__ b2,
    const float* __restrict__ w3, const float* __restrict__ b3,
    float* __restrict__ scores)
{
  int bid = blockIdx.x;        // 1024 blocks: b(4) x r(4) x it(8) x jt(8)
  int jt = bid & 7;
  int it = (bid >> 3) & 7;
  int r  = (bid >> 6) & 3;
  int b  = bid >> 8;
  int t = threadIdx.x;
  int ti = t >> 4, tj = t & 15;
  __shared__ float h1s[16][257];   // +1 pad: ti/tj-indexed reads hit distinct banks
  __shared__ float h2s[16][257];
  __shared__ __align__(16) float W2s[64][128];
  __shared__ float b2s[128], w3s[128];
  for (int idx = t; idx < 4096; idx += 256) {
    int ii = idx >> 8, d = idx & 255;
    h1s[ii][d] = h1p[((b * 4 + r) * 128 + it * 16 + ii) * 256 + d];
    h2s[ii][d] = h2 [((b * 4 + r) * 128 + jt * 16 + ii) * 256 + d];
  }
  if (t < 128) { b2s[t] = b2[r * 128 + t]; w3s[t] = w3[r * 128 + t]; }
  float acc[128];
  #pragma unroll
  for (int e = 0; e < 128; ++e) acc[e] = 0.f;
  for (int dc = 0; dc < 4; ++dc) {
    __syncthreads();             // covers staging (dc=0) and prior-chunk reads (dc>0)
    for (int idx = t; idx < 8192; idx += 256) {
      int dd = idx >> 7, e = idx & 127;
      W2s[dd][e] = W2[(r * 256 + dc * 64 + dd) * 128 + e];
    }
    __syncthreads();
    for (int dd = 0; dd < 64; ++dd) {
      float v = h1s[ti][dc * 64 + dd] + h2s[tj][dc * 64 + dd];
      v = fmaxf(v, 0.f);
      #pragma unroll
      for (int e4 = 0; e4 < 32; ++e4) {
        float4 w = *reinterpret_cast<const float4*>(&W2s[dd][e4 * 4]);
        acc[e4 * 4 + 0] = fmaf(v, w.x, acc[e4 * 4 + 0]);
        acc[e4 * 4 + 1] = fmaf(v, w.y, acc[e4 * 4 + 1]);
        acc[e4 * 4 + 2] = fmaf(v, w.z, acc[e4 * 4 + 2]);
        acc[e4 * 4 + 3] = fmaf(v, w.w, acc[e4 * 4 + 3]);
      }
    }
  }
  float s = b3[r];
  #pragma unroll
  for (int e = 0; e < 128; ++e)
    s = fmaf(w3s[e], fmaxf(acc[e] + b2s[e], 0.f), s);
  scores[((b * 4 + r) * 128 + it * 16 + ti) * 128 + jt * 16 + tj] = s;
}

__global__ __launch_bounds__(128) void k_softmax_rel(
    const float* __restrict__ scores, const float* __restrict__ f2,
    float* __restrict__ all_rel)
{
  int bid = blockIdx.x;        // 2048 blocks: b(4) x r(4) x i(128)
  int i = bid & 127;
  int r = (bid >> 7) & 3;
  int b = bid >> 9;
  int t = threadIdx.x;         // 0..127
  __shared__ float sraw[128];
  __shared__ float p[128];
  float s = scores[((b * 4 + r) * 128 + i) * 128 + t];
  sraw[t] = s;
  __syncthreads();
  float m = -1e30f;
  for (int j = 0; j < 128; ++j) m = fmaxf(m, sraw[j]);
  float pv = expf(s - m);
  p[t] = pv;
  __syncthreads();
  float sum = 0.f;
  for (int j = 0; j < 128; ++j) sum += p[j];
  float inv = 1.f / sum;
  for (int d = t; d < 256; d += 128) {
    float a = 0.f;
    for (int j = 0; j < 128; ++j)
      a = fmaf(p[j], f2[(b * 128 + j) * 256 + d], a);
    all_rel[(b * 128 + i) * 1024 + r * 256 + d] = a * inv;
  }
}

// Generic C[M,N] = act(A[M,K] @ W[K,N] + bias[N]); grid = (N/64, M/16), 256 thr.
__global__ __launch_bounds__(256) void gemm_bias_act(
    const float* __restrict__ A, const float* __restrict__ W,
    const float* __restrict__ bias, float* __restrict__ C,
    int M, int K, int N, int act)
{
  int ct = blockIdx.x, rt = blockIdx.y;
  int t = threadIdx.x;
  int tc = t & 63;             // col within 64-wide tile
  int tr = t >> 6;             // 0..3 -> 4-row group
  int col = ct * 64 + tc;
  __shared__ float As[16][128];
  float acc[4] = {0.f, 0.f, 0.f, 0.f};
  for (int kc = 0; kc < K; kc += 128) {
    for (int idx = t; idx < 16 * 128; idx += 256) {
      int ii = idx >> 7, kk = idx & 127;
      As[ii][kk] = A[(rt * 16 + ii) * K + kc + kk];
    }
    __syncthreads();
    for (int kk = 0; kk < 128; ++kk) {
      float wv = W[(kc + kk) * N + col];
      #pragma unroll
      for (int q = 0; q < 4; ++q)
        acc[q] = fmaf(As[tr * 4 + q][kk], wv, acc[q]);
    }
    __syncthreads();
  }
  float bv = bias[col];
  #pragma unroll
  for (int q = 0; q < 4; ++q) {
    float v = acc[q] + bv;
    if (act) v = fmaxf(v, 0.f);
    C[(rt * 16 + tr * 4 + q) * N + col] = v;
  }
}

extern "C" void kernel_launch(void* const* d_in, const int* in_sizes, int n_in,
                              void* d_out, int out_size, void* d_ws, size_t ws_size,
                              hipStream_t stream) {
  const float* f1  = (const float*)d_in[0];
  const float* f2  = (const float*)d_in[1];
  const float* W1  = (const float*)d_in[2];
  const float* b1  = (const float*)d_in[3];
  const float* W2  = (const float*)d_in[4];
  const float* b2  = (const float*)d_in[5];
  const float* w3  = (const float*)d_in[6];
  const float* b3  = (const float*)d_in[7];
  const float* Wa1 = (const float*)d_in[8];
  const float* ba1 = (const float*)d_in[9];
  const float* Wa2 = (const float*)d_in[10];
  const float* ba2 = (const float*)d_in[11];
  float* out = (float*)d_out;
  float* ws = (float*)d_ws;

  float* h1p     = ws;                 // 524288 floats
  float* h2      = ws + 524288;        // 524288
  float* scores  = ws + 1048576;       // 262144
  float* all_rel = ws + 1310720;       // 524288
  float* hidden  = ws + 1835008;       // 262144   (total 8 MB)

  hipLaunchKernelGGL(k_proj, dim3(256), dim3(256), 0, stream,
                     f1, f2, W1, b1, h1p, h2);
  hipLaunchKernelGGL(k_scores, dim3(1024), dim3(256), 0, stream,
                     h1p, h2, W2, b2, w3, b3, scores);
  hipLaunchKernelGGL(k_softmax_rel, dim3(2048), dim3(128), 0, stream,
                     scores, f2, all_rel);
  hipLaunchKernelGGL(gemm_bias_act, dim3(8, 32), dim3(256), 0, stream,
                     all_rel, Wa1, ba1, hidden, 512, 1024, 512, 1);
  hipLaunchKernelGGL(gemm_bias_act, dim3(4, 32), dim3(256), 0, stream,
                     hidden, Wa2, ba2, out, 512, 512, 256, 0);
}

// Round 2
// 471.208 us; speedup vs baseline: 2.0359x; 2.0359x over previous
//
#include <hip/hip_runtime.h>

// Shapes: B=4, N1=N2=128, D=256, R=4, E=D/2=128
// Pipeline:
//   A: h1p[b,r,i,e] = f1[b,i,:]@W1[r,:256,e] + b1[r,e];  h2[b,r,j,e] = f2[b,j,:]@W1[r,256:,e]
//   B: scores[b,r,i,j] = w3[r,:] . relu(W2[r]^T relu(h1p_i + h2_j) + b2[r]) + b3[r]   [MFMA bf16]
//   C: w = softmax_j(scores); all_rel[b,i,r*256+d] = sum_j w_ij f2[b,j,d]
//   D: out = relu(all_rel @ Wa1 + ba1) @ Wa2 + ba2

typedef __bf16 bf16x8 __attribute__((ext_vector_type(8)));
typedef float f32x16 __attribute__((ext_vector_type(16)));

#define RS 268   // h-tile row stride (floats): 16B-aligned rows, bank stride 12 -> <=2-way

static __device__ __forceinline__ ushort f2b(float f) {
  __bf16 h = (__bf16)f;
  return __builtin_bit_cast(ushort, h);
}

__global__ __launch_bounds__(256) void k_proj(
    const float* __restrict__ f1, const float* __restrict__ f2,
    const float* __restrict__ W1, const float* __restrict__ b1,
    float* __restrict__ h1p, float* __restrict__ h2)
{
  int bid = blockIdx.x;        // 256 blocks: half(2) x b(4) x r(4) x it(8)
  int half = bid >> 7;
  int rem  = bid & 127;
  int b  = rem >> 5;
  int r  = (rem >> 3) & 3;
  int it = rem & 7;
  int t = threadIdx.x;         // e = t (0..255)
  __shared__ float As[16][256];
  const float* f = half ? f2 : f1;
  for (int idx = t; idx < 16 * 256; idx += 256) {
    int ii = idx >> 8, d = idx & 255;
    As[ii][d] = f[(b * 128 + it * 16 + ii) * 256 + d];
  }
  __syncthreads();
  float acc[16];
  #pragma unroll
  for (int ii = 0; ii < 16; ++ii) acc[ii] = 0.f;
  const float* Wg = W1 + (r * 512 + (half ? 256 : 0)) * 256 + t;
  for (int d = 0; d < 256; ++d) {
    float wv = Wg[d * 256];
    #pragma unroll
    for (int ii = 0; ii < 16; ++ii)
      acc[ii] = fmaf(As[ii][d], wv, acc[ii]);
  }
  float bb = half ? 0.f : b1[r * 256 + t];
  float* ho = half ? h2 : h1p;
  #pragma unroll
  for (int ii = 0; ii < 16; ++ii)
    ho[((b * 4 + r) * 128 + it * 16 + ii) * 256 + t] = acc[ii] + bb;
}

// Pre-swizzle W2 (fp32) into bf16 B-operand fragment order for mfma_f32_32x32x16_bf16:
// W2swz[r][ks(16)][ct(4)][lane(64)][j(8)], element j of lane l is
//   W2[r][ d = ks*16 + (j>>2)*8 + (l>>5)*4 + (j&3) ][ e = ct*32 + (l&31) ]
__global__ __launch_bounds__(256) void k_w2swz(
    const float* __restrict__ W2, ushort* __restrict__ W2swz)
{
  int bid = blockIdx.x;          // 64 blocks: r(4) x ks(16)
  int r = bid >> 4, ks = bid & 15;
  int t = threadIdx.x;
  int ct = t >> 6, l = t & 63;
  ushort us[8];
  #pragma unroll
  for (int j = 0; j < 8; ++j) {
    int d = ks * 16 + ((j >> 2) * 8) + ((l >> 5) * 4) + (j & 3);
    int e = ct * 32 + (l & 31);
    us[j] = f2b(W2[(r * 256 + d) * 128 + e]);
  }
  uint4 pk;
  pk.x = (uint)us[0] | ((uint)us[1] << 16);
  pk.y = (uint)us[2] | ((uint)us[3] << 16);
  pk.z = (uint)us[4] | ((uint)us[5] << 16);
  pk.w = (uint)us[6] | ((uint)us[7] << 16);
  *(uint4*)&W2swz[(((r * 16 + ks) * 4 + ct) * 64 + l) * 8] = pk;
}

// MFMA scores kernel. Block = (b,r,it,jt) 16x16 (i,j) pair tile = 256 implicit A-rows,
// K=256, N=128. A[p][k] = relu(h1[i_p][k] + h2[j_p][k]) built per 16-wide k-step into
// LDS in fragment order (lane's 8 bf16 contiguous). 4 waves; wave owns 2 row-tiles of 32.
__global__ __launch_bounds__(256, 2) void k_scores_mfma(
    const float* __restrict__ h1p, const float* __restrict__ h2,
    const ushort* __restrict__ W2swz, const float* __restrict__ b2,
    const float* __restrict__ w3, const float* __restrict__ b3,
    float* __restrict__ scores)
{
  int bid = blockIdx.x;        // 1024 blocks: b(4) x r(4) x it(8) x jt(8)
  int jt = bid & 7;
  int it = (bid >> 3) & 7;
  int r  = (bid >> 6) & 3;
  int b  = bid >> 8;
  int t = threadIdx.x, w = t >> 6, l = t & 63;
  __shared__ float h1s[16][RS];
  __shared__ float h2s[16][RS];
  __shared__ __align__(16) ushort A_lds[2][8 * 64 * 8];   // [buf][rt][lane][j] 8KB each

  const float* h1g = h1p + ((b * 4 + r) * 128 + it * 16) * 256;
  const float* h2g = h2  + ((b * 4 + r) * 128 + jt * 16) * 256;
  for (int idx = t; idx < 1024; idx += 256) {
    int ii = idx >> 6, d4 = (idx & 63) << 2;
    *(float4*)&h1s[ii][d4] = *(const float4*)&h1g[ii * 256 + d4];
    *(float4*)&h2s[ii][d4] = *(const float4*)&h2g[ii * 256 + d4];
  }

  f32x16 acc[2][4];
  #pragma unroll
  for (int q = 0; q < 2; ++q)
    #pragma unroll
    for (int c = 0; c < 4; ++c)
      #pragma unroll
      for (int e = 0; e < 16; ++e) acc[q][c][e] = 0.f;

  const ushort* bptr = W2swz + r * (16 * 4 * 64 * 8);
  int kb_lane = (l >> 5) << 2;   // 0 or 4 (k sub-offset per lane half)
  int m31 = l & 31;              // A-row within 32-row tile / B-col within 32
  int jrow = l & 15;             // j index of the pair (p & 15)

  __syncthreads();

  for (int ks = 0; ks < 16; ++ks) {
    int buf = ks & 1;
    // ---- build A chunk (k in [ks*16, ks*16+16)) in fragment order ----
    #pragma unroll
    for (int q = 0; q < 2; ++q) {
      int rt = w * 2 + q;
      int p = rt * 32 + m31;     // pair index 0..255 (ti = p>>4, tj = p&15)
      int irow = p >> 4;
      int kb0 = ks * 16 + kb_lane;
      float4 xa = *(const float4*)&h1s[irow][kb0];
      float4 xb = *(const float4*)&h1s[irow][kb0 + 8];
      float4 ya = *(const float4*)&h2s[jrow][kb0];
      float4 yb = *(const float4*)&h2s[jrow][kb0 + 8];
      float v0 = fmaxf(xa.x + ya.x, 0.f), v1 = fmaxf(xa.y + ya.y, 0.f);
      float v2 = fmaxf(xa.z + ya.z, 0.f), v3 = fmaxf(xa.w + ya.w, 0.f);
      float v4 = fmaxf(xb.x + yb.x, 0.f), v5 = fmaxf(xb.y + yb.y, 0.f);
      float v6 = fmaxf(xb.z + yb.z, 0.f), v7 = fmaxf(xb.w + yb.w, 0.f);
      uint4 pk;
      pk.x = (uint)f2b(v0) | ((uint)f2b(v1) << 16);
      pk.y = (uint)f2b(v2) | ((uint)f2b(v3) << 16);
      pk.z = (uint)f2b(v4) | ((uint)f2b(v5) << 16);
      pk.w = (uint)f2b(v6) | ((uint)f2b(v7) << 16);
      *(uint4*)&A_lds[buf][(rt * 64 + l) * 8] = pk;
    }
    __syncthreads();   // A chunk ready (also licenses overwrite of buf^1 next iter)
    // ---- MFMA ----
    uint4 a0r = *(const uint4*)&A_lds[buf][((w * 2 + 0) * 64 + l) * 8];
    uint4 a1r = *(const uint4*)&A_lds[buf][((w * 2 + 1) * 64 + l) * 8];
    bf16x8 af0 = __builtin_bit_cast(bf16x8, a0r);
    bf16x8 af1 = __builtin_bit_cast(bf16x8, a1r);
    #pragma unroll
    for (int ct = 0; ct < 4; ++ct) {
      uint4 braw = *(const uint4*)&bptr[((ks * 4 + ct) * 64 + l) * 8];
      bf16x8 bfr = __builtin_bit_cast(bf16x8, braw);
      acc[0][ct] = __builtin_amdgcn_mfma_f32_32x32x16_bf16(af0, bfr, acc[0][ct], 0, 0, 0);
      acc[1][ct] = __builtin_amdgcn_mfma_f32_32x32x16_bf16(af1, bfr, acc[1][ct], 0, 0, 0);
    }
  }

  // ---- epilogue: s[p] = sum_e w3[e]*relu(g[p][e]+b2[e]) + b3 ----
  // C/D layout (32x32): col = lane&31, row = (reg&3) + 8*(reg>>2) + 4*(lane>>5)
  float b3v = b3[r];
  float* sc_base = scores + (((b * 4 + r) * 128 + it * 16) * 128) + jt * 16;
  #pragma unroll
  for (int q = 0; q < 2; ++q) {
    float sp[16];
    #pragma unroll
    for (int g = 0; g < 16; ++g) sp[g] = 0.f;
    #pragma unroll
    for (int ct = 0; ct < 4; ++ct) {
      int e = ct * 32 + m31;
      float w3v = w3[r * 128 + e];
      float b2v = b2[r * 128 + e];
      #pragma unroll
      for (int g = 0; g < 16; ++g)
        sp[g] = fmaf(w3v, fmaxf(acc[q][ct][g] + b2v, 0.f), sp[g]);
    }
    #pragma unroll
    for (int off = 16; off >= 1; off >>= 1)
      #pragma unroll
      for (int g = 0; g < 16; ++g)
        sp[g] += __shfl_xor(sp[g], off, 64);
    if (m31 == 0) {
      int half4 = (l >> 5) << 2;
      #pragma unroll
      for (int g = 0; g < 16; ++g) {
        int p = (w * 2 + q) * 32 + (g & 3) + 8 * (g >> 2) + half4;
        sc_base[(p >> 4) * 128 + (p & 15)] = sp[g] + b3v;
      }
    }
  }
}

__global__ __launch_bounds__(128) void k_softmax_rel(
    const float* __restrict__ scores, const float* __restrict__ f2,
    float* __restrict__ all_rel)
{
  int bid = blockIdx.x;        // 2048 blocks: b(4) x r(4) x i(128)
  int i = bid & 127;
  int r = (bid >> 7) & 3;
  int b = bid >> 9;
  int t = threadIdx.x;         // 0..127
  __shared__ float sraw[128];
  __shared__ float p[128];
  float s = scores[((b * 4 + r) * 128 + i) * 128 + t];
  sraw[t] = s;
  __syncthreads();
  float m = -1e30f;
  for (int j = 0; j < 128; ++j) m = fmaxf(m, sraw[j]);
  float pv = expf(s - m);
  p[t] = pv;
  __syncthreads();
  float sum = 0.f;
  for (int j = 0; j < 128; ++j) sum += p[j];
  float inv = 1.f / sum;
  for (int d = t; d < 256; d += 128) {
    float a = 0.f;
    for (int j = 0; j < 128; ++j)
      a = fmaf(p[j], f2[(b * 128 + j) * 256 + d], a);
    all_rel[(b * 128 + i) * 1024 + r * 256 + d] = a * inv;
  }
}

// Generic C[M,N] = act(A[M,K] @ W[K,N] + bias[N]); grid = (N/64, M/16), 256 thr.
__global__ __launch_bounds__(256) void gemm_bias_act(
    const float* __restrict__ A, const float* __restrict__ W,
    const float* __restrict__ bias, float* __restrict__ C,
    int M, int K, int N, int act)
{
  int ct = blockIdx.x, rt = blockIdx.y;
  int t = threadIdx.x;
  int tc = t & 63;             // col within 64-wide tile
  int tr = t >> 6;             // 0..3 -> 4-row group
  int col = ct * 64 + tc;
  __shared__ float As[16][128];
  float acc[4] = {0.f, 0.f, 0.f, 0.f};
  for (int kc = 0; kc < K; kc += 128) {
    for (int idx = t; idx < 16 * 128; idx += 256) {
      int ii = idx >> 7, kk = idx & 127;
      As[ii][kk] = A[(rt * 16 + ii) * K + kc + kk];
    }
    __syncthreads();
    for (int kk = 0; kk < 128; ++kk) {
      float wv = W[(kc + kk) * N + col];
      #pragma unroll
      for (int q = 0; q < 4; ++q)
        acc[q] = fmaf(As[tr * 4 + q][kk], wv, acc[q]);
    }
    __syncthreads();
  }
  float bv = bias[col];
  #pragma unroll
  for (int q = 0; q < 4; ++q) {
    float v = acc[q] + bv;
    if (act) v = fmaxf(v, 0.f);
    C[(rt * 16 + tr * 4 + q) * N + col] = v;
  }
}

extern "C" void kernel_launch(void* const* d_in, const int* in_sizes, int n_in,
                              void* d_out, int out_size, void* d_ws, size_t ws_size,
                              hipStream_t stream) {
  const float* f1  = (const float*)d_in[0];
  const float* f2  = (const float*)d_in[1];
  const float* W1  = (const float*)d_in[2];
  const float* b1  = (const float*)d_in[3];
  const float* W2  = (const float*)d_in[4];
  const float* b2  = (const float*)d_in[5];
  const float* w3  = (const float*)d_in[6];
  const float* b3  = (const float*)d_in[7];
  const float* Wa1 = (const float*)d_in[8];
  const float* ba1 = (const float*)d_in[9];
  const float* Wa2 = (const float*)d_in[10];
  const float* ba2 = (const float*)d_in[11];
  float* out = (float*)d_out;
  float* ws = (float*)d_ws;

  float* h1p     = ws;                 // 524288 floats
  float* h2      = ws + 524288;        // 524288
  float* scores  = ws + 1048576;       // 262144
  float* all_rel = ws + 1310720;       // 524288
  float* hidden  = ws + 1835008;       // 262144 (total 8 MB)
  // W2swz (256 KB of bf16 frags) aliases the `hidden` region: it is dead before
  // gemm1 writes hidden (k_w2swz + k_scores_mfma complete first on the stream).
  ushort* W2swz  = (ushort*)(ws + 1835008);

  hipLaunchKernelGGL(k_w2swz, dim3(64), dim3(256), 0, stream, W2, W2swz);
  hipLaunchKernelGGL(k_proj, dim3(256), dim3(256), 0, stream,
                     f1, f2, W1, b1, h1p, h2);
  hipLaunchKernelGGL(k_scores_mfma, dim3(1024), dim3(256), 0, stream,
                     h1p, h2, W2swz, b2, w3, b3, scores);
  hipLaunchKernelGGL(k_softmax_rel, dim3(2048), dim3(128), 0, stream,
                     scores, f2, all_rel);
  hipLaunchKernelGGL(gemm_bias_act, dim3(8, 32), dim3(256), 0, stream,
                     all_rel, Wa1, ba1, hidden, 512, 1024, 512, 1);
  hipLaunchKernelGGL(gemm_bias_act, dim3(4, 32), dim3(256), 0, stream,
                     hidden, Wa2, ba2, out, 512, 512, 256, 0);
}

// Round 3
// 132.751 us; speedup vs baseline: 7.2265x; 3.5496x over previous
//
#include <hip/hip_runtime.h>

// Shapes: B=4, N1=N2=128, D=256, R=4, E=D/2=128
// Pipeline:
//   A: h1p[b,r,i,e] = f1[b,i,:]@W1[r,:256,e] + b1[r,e];  h2[b,r,j,e] = f2[b,j,:]@W1[r,256:,e]
//   B: scores[b,r,i,j] = w3[r,:] . relu(W2[r]^T relu(h1p_i + h2_j) + b2[r]) + b3[r]   [MFMA bf16]
//   C: w = softmax_j(scores); all_rel[b,i,r*256+d] = sum_j w_ij f2[b,j,d]
//   D: out = relu(all_rel @ Wa1 + ba1) @ Wa2 + ba2     [fp32 tiled GEMM]

typedef __bf16 bf16x8 __attribute__((ext_vector_type(8)));
typedef float f32x16 __attribute__((ext_vector_type(16)));

#define RS 268

static __device__ __forceinline__ ushort f2b(float f) {
  __bf16 h = (__bf16)f;
  return __builtin_bit_cast(ushort, h);
}

// ---------------- fp32 tiled GEMM: C[M,N] = act(A @ W + bias) ----------------
// 64x64 tile, 256 thr, 4x4 micro-tile, KC=32 in LDS, reg-prefetch next chunk.
__global__ __launch_bounds__(256) void gemm_tile(
    const float* __restrict__ A, const float* __restrict__ W,
    const float* __restrict__ bias, float* __restrict__ C,
    int M, int K, int N, int act)
{
  int ct = blockIdx.x, rt = blockIdx.y;
  int t = threadIdx.x;
  int tm = t & 15, tn = t >> 4;          // compute roles
  int arow = t & 63, akq = t >> 6;       // A staging: row 0..63, k-quad 0..3
  int bn4 = (t & 15) * 4, bk = t >> 4;   // B staging: col4, k-row 0..15
  __shared__ __align__(16) float As[32][64];   // [k][m]
  __shared__ __align__(16) float Bs[32][64];   // [k][n]

  const float* Ab = A + (rt * 64 + arow) * K;
  const float* Wb = W + ct * 64 + bn4;

  float4 pa0 = *(const float4*)&Ab[akq * 8 + 0];
  float4 pa1 = *(const float4*)&Ab[akq * 8 + 4];
  float4 pb0 = *(const float4*)&Wb[(size_t)bk * N];
  float4 pb1 = *(const float4*)&Wb[(size_t)(bk + 16) * N];

  float acc[4][4];
  #pragma unroll
  for (int i = 0; i < 4; ++i)
    #pragma unroll
    for (int j = 0; j < 4; ++j) acc[i][j] = 0.f;

  for (int kc = 0; kc < K; kc += 32) {
    __syncthreads();               // readers of previous chunk done
    As[akq * 8 + 0][arow] = pa0.x;
    As[akq * 8 + 1][arow] = pa0.y;
    As[akq * 8 + 2][arow] = pa0.z;
    As[akq * 8 + 3][arow] = pa0.w;
    As[akq * 8 + 4][arow] = pa1.x;
    As[akq * 8 + 5][arow] = pa1.y;
    As[akq * 8 + 6][arow] = pa1.z;
    As[akq * 8 + 7][arow] = pa1.w;
    *(float4*)&Bs[bk][bn4] = pb0;
    *(float4*)&Bs[bk + 16][bn4] = pb1;
    __syncthreads();
    if (kc + 32 < K) {             // prefetch next chunk (overlaps compute below)
      pa0 = *(const float4*)&Ab[kc + 32 + akq * 8];
      pa1 = *(const float4*)&Ab[kc + 32 + akq * 8 + 4];
      pb0 = *(const float4*)&Wb[(size_t)(kc + 32 + bk) * N];
      pb1 = *(const float4*)&Wb[(size_t)(kc + 32 + bk + 16) * N];
    }
    #pragma unroll
    for (int kk = 0; kk < 32; ++kk) {
      float4 a = *(const float4*)&As[kk][tm * 4];
      float4 w = *(const float4*)&Bs[kk][tn * 4];
      acc[0][0] = fmaf(a.x, w.x, acc[0][0]); acc[0][1] = fmaf(a.x, w.y, acc[0][1]);
      acc[0][2] = fmaf(a.x, w.z, acc[0][2]); acc[0][3] = fmaf(a.x, w.w, acc[0][3]);
      acc[1][0] = fmaf(a.y, w.x, acc[1][0]); acc[1][1] = fmaf(a.y, w.y, acc[1][1]);
      acc[1][2] = fmaf(a.y, w.z, acc[1][2]); acc[1][3] = fmaf(a.y, w.w, acc[1][3]);
      acc[2][0] = fmaf(a.z, w.x, acc[2][0]); acc[2][1] = fmaf(a.z, w.y, acc[2][1]);
      acc[2][2] = fmaf(a.z, w.z, acc[2][2]); acc[2][3] = fmaf(a.z, w.w, acc[2][3]);
      acc[3][0] = fmaf(a.w, w.x, acc[3][0]); acc[3][1] = fmaf(a.w, w.y, acc[3][1]);
      acc[3][2] = fmaf(a.w, w.z, acc[3][2]); acc[3][3] = fmaf(a.w, w.w, acc[3][3]);
    }
  }

  int col = ct * 64 + tn * 4;
  float4 bv = *(const float4*)&bias[col];
  #pragma unroll
  for (int qm = 0; qm < 4; ++qm) {
    int row = rt * 64 + tm * 4 + qm;
    float4 ov;
    ov.x = acc[qm][0] + bv.x; ov.y = acc[qm][1] + bv.y;
    ov.z = acc[qm][2] + bv.z; ov.w = acc[qm][3] + bv.w;
    if (act) {
      ov.x = fmaxf(ov.x, 0.f); ov.y = fmaxf(ov.y, 0.f);
      ov.z = fmaxf(ov.z, 0.f); ov.w = fmaxf(ov.w, 0.f);
    }
    *(float4*)&C[(size_t)row * N + col] = ov;
  }
}

// ---------------- projection as batched tiled GEMM ----------------
// grid (ct=4, rt=2, z=32): z -> (half, b, r). M=128, K=256, N=256 per batch.
__global__ __launch_bounds__(256) void k_proj2(
    const float* __restrict__ f1, const float* __restrict__ f2,
    const float* __restrict__ W1, const float* __restrict__ b1,
    float* __restrict__ h1p, float* __restrict__ h2)
{
  int z = blockIdx.z;
  int half = z >> 4, b = (z >> 2) & 3, r = z & 3;
  int ct = blockIdx.x, rt = blockIdx.y;
  int t = threadIdx.x;
  int tm = t & 15, tn = t >> 4;
  int arow = t & 63, akq = t >> 6;
  int bn4 = (t & 15) * 4, bk = t >> 4;
  __shared__ __align__(16) float As[32][64];
  __shared__ __align__(16) float Bs[32][64];

  const float* A = (half ? f2 : f1) + (size_t)b * 128 * 256;
  const float* W = W1 + (size_t)(r * 512 + half * 256) * 256;

  const float* Ab = A + (rt * 64 + arow) * 256;
  const float* Wb = W + ct * 64 + bn4;

  float4 pa0 = *(const float4*)&Ab[akq * 8 + 0];
  float4 pa1 = *(const float4*)&Ab[akq * 8 + 4];
  float4 pb0 = *(const float4*)&Wb[bk * 256];
  float4 pb1 = *(const float4*)&Wb[(bk + 16) * 256];

  float acc[4][4];
  #pragma unroll
  for (int i = 0; i < 4; ++i)
    #pragma unroll
    for (int j = 0; j < 4; ++j) acc[i][j] = 0.f;

  for (int kc = 0; kc < 256; kc += 32) {
    __syncthreads();
    As[akq * 8 + 0][arow] = pa0.x;
    As[akq * 8 + 1][arow] = pa0.y;
    As[akq * 8 + 2][arow] = pa0.z;
    As[akq * 8 + 3][arow] = pa0.w;
    As[akq * 8 + 4][arow] = pa1.x;
    As[akq * 8 + 5][arow] = pa1.y;
    As[akq * 8 + 6][arow] = pa1.z;
    As[akq * 8 + 7][arow] = pa1.w;
    *(float4*)&Bs[bk][bn4] = pb0;
    *(float4*)&Bs[bk + 16][bn4] = pb1;
    __syncthreads();
    if (kc + 32 < 256) {
      pa0 = *(const float4*)&Ab[kc + 32 + akq * 8];
      pa1 = *(const float4*)&Ab[kc + 32 + akq * 8 + 4];
      pb0 = *(const float4*)&Wb[(kc + 32 + bk) * 256];
      pb1 = *(const float4*)&Wb[(kc + 32 + bk + 16) * 256];
    }
    #pragma unroll
    for (int kk = 0; kk < 32; ++kk) {
      float4 a = *(const float4*)&As[kk][tm * 4];
      float4 w = *(const float4*)&Bs[kk][tn * 4];
      acc[0][0] = fmaf(a.x, w.x, acc[0][0]); acc[0][1] = fmaf(a.x, w.y, acc[0][1]);
      acc[0][2] = fmaf(a.x, w.z, acc[0][2]); acc[0][3] = fmaf(a.x, w.w, acc[0][3]);
      acc[1][0] = fmaf(a.y, w.x, acc[1][0]); acc[1][1] = fmaf(a.y, w.y, acc[1][1]);
      acc[1][2] = fmaf(a.y, w.z, acc[1][2]); acc[1][3] = fmaf(a.y, w.w, acc[1][3]);
      acc[2][0] = fmaf(a.z, w.x, acc[2][0]); acc[2][1] = fmaf(a.z, w.y, acc[2][1]);
      acc[2][2] = fmaf(a.z, w.z, acc[2][2]); acc[2][3] = fmaf(a.z, w.w, acc[2][3]);
      acc[3][0] = fmaf(a.w, w.x, acc[3][0]); acc[3][1] = fmaf(a.w, w.y, acc[3][1]);
      acc[3][2] = fmaf(a.w, w.z, acc[3][2]); acc[3][3] = fmaf(a.w, w.w, acc[3][3]);
    }
  }

  int col = ct * 64 + tn * 4;
  float4 bv;
  if (half) { bv.x = bv.y = bv.z = bv.w = 0.f; }
  else      { bv = *(const float4*)&b1[r * 256 + col]; }
  float* ho = half ? h2 : h1p;
  #pragma unroll
  for (int qm = 0; qm < 4; ++qm) {
    int row = rt * 64 + tm * 4 + qm;
    float4 ov;
    ov.x = acc[qm][0] + bv.x; ov.y = acc[qm][1] + bv.y;
    ov.z = acc[qm][2] + bv.z; ov.w = acc[qm][3] + bv.w;
    *(float4*)&ho[((size_t)(b * 4 + r) * 128 + row) * 256 + col] = ov;
  }
}

// ---------------- W2 pre-swizzle (B-fragment order for 32x32x16 bf16) ----------------
__global__ __launch_bounds__(256) void k_w2swz(
    const float* __restrict__ W2, ushort* __restrict__ W2swz)
{
  int bid = blockIdx.x;          // 64 blocks: r(4) x ks(16)
  int r = bid >> 4, ks = bid & 15;
  int t = threadIdx.x;
  int ct = t >> 6, l = t & 63;
  ushort us[8];
  #pragma unroll
  for (int j = 0; j < 8; ++j) {
    int d = ks * 16 + ((j >> 2) * 8) + ((l >> 5) * 4) + (j & 3);
    int e = ct * 32 + (l & 31);
    us[j] = f2b(W2[(r * 256 + d) * 128 + e]);
  }
  uint4 pk;
  pk.x = (uint)us[0] | ((uint)us[1] << 16);
  pk.y = (uint)us[2] | ((uint)us[3] << 16);
  pk.z = (uint)us[4] | ((uint)us[5] << 16);
  pk.w = (uint)us[6] | ((uint)us[7] << 16);
  *(uint4*)&W2swz[(((r * 16 + ks) * 4 + ct) * 64 + l) * 8] = pk;
}

// ---------------- MFMA scores kernel ----------------
__global__ __launch_bounds__(256, 2) void k_scores_mfma(
    const float* __restrict__ h1p, const float* __restrict__ h2,
    const ushort* __restrict__ W2swz, const float* __restrict__ b2,
    const float* __restrict__ w3, const float* __restrict__ b3,
    float* __restrict__ scores)
{
  int bid = blockIdx.x;        // 1024 blocks: b(4) x r(4) x it(8) x jt(8)
  int jt = bid & 7;
  int it = (bid >> 3) & 7;
  int r  = (bid >> 6) & 3;
  int b  = bid >> 8;
  int t = threadIdx.x, w = t >> 6, l = t & 63;
  __shared__ float h1s[16][RS];
  __shared__ float h2s[16][RS];
  __shared__ __align__(16) ushort A_lds[2][8 * 64 * 8];

  const float* h1g = h1p + ((b * 4 + r) * 128 + it * 16) * 256;
  const float* h2g = h2  + ((b * 4 + r) * 128 + jt * 16) * 256;
  for (int idx = t; idx < 1024; idx += 256) {
    int ii = idx >> 6, d4 = (idx & 63) << 2;
    *(float4*)&h1s[ii][d4] = *(const float4*)&h1g[ii * 256 + d4];
    *(float4*)&h2s[ii][d4] = *(const float4*)&h2g[ii * 256 + d4];
  }

  f32x16 acc[2][4];
  #pragma unroll
  for (int q = 0; q < 2; ++q)
    #pragma unroll
    for (int c = 0; c < 4; ++c)
      #pragma unroll
      for (int e = 0; e < 16; ++e) acc[q][c][e] = 0.f;

  const ushort* bptr = W2swz + r * (16 * 4 * 64 * 8);
  int kb_lane = (l >> 5) << 2;
  int m31 = l & 31;
  int jrow = l & 15;

  __syncthreads();

  for (int ks = 0; ks < 16; ++ks) {
    int buf = ks & 1;
    #pragma unroll
    for (int q = 0; q < 2; ++q) {
      int rt = w * 2 + q;
      int p = rt * 32 + m31;
      int irow = p >> 4;
      int kb0 = ks * 16 + kb_lane;
      float4 xa = *(const float4*)&h1s[irow][kb0];
      float4 xb = *(const float4*)&h1s[irow][kb0 + 8];
      float4 ya = *(const float4*)&h2s[jrow][kb0];
      float4 yb = *(const float4*)&h2s[jrow][kb0 + 8];
      float v0 = fmaxf(xa.x + ya.x, 0.f), v1 = fmaxf(xa.y + ya.y, 0.f);
      float v2 = fmaxf(xa.z + ya.z, 0.f), v3 = fmaxf(xa.w + ya.w, 0.f);
      float v4 = fmaxf(xb.x + yb.x, 0.f), v5 = fmaxf(xb.y + yb.y, 0.f);
      float v6 = fmaxf(xb.z + yb.z, 0.f), v7 = fmaxf(xb.w + yb.w, 0.f);
      uint4 pk;
      pk.x = (uint)f2b(v0) | ((uint)f2b(v1) << 16);
      pk.y = (uint)f2b(v2) | ((uint)f2b(v3) << 16);
      pk.z = (uint)f2b(v4) | ((uint)f2b(v5) << 16);
      pk.w = (uint)f2b(v6) | ((uint)f2b(v7) << 16);
      *(uint4*)&A_lds[buf][(rt * 64 + l) * 8] = pk;
    }
    __syncthreads();
    uint4 a0r = *(const uint4*)&A_lds[buf][((w * 2 + 0) * 64 + l) * 8];
    uint4 a1r = *(const uint4*)&A_lds[buf][((w * 2 + 1) * 64 + l) * 8];
    bf16x8 af0 = __builtin_bit_cast(bf16x8, a0r);
    bf16x8 af1 = __builtin_bit_cast(bf16x8, a1r);
    #pragma unroll
    for (int ct = 0; ct < 4; ++ct) {
      uint4 braw = *(const uint4*)&bptr[((ks * 4 + ct) * 64 + l) * 8];
      bf16x8 bfr = __builtin_bit_cast(bf16x8, braw);
      acc[0][ct] = __builtin_amdgcn_mfma_f32_32x32x16_bf16(af0, bfr, acc[0][ct], 0, 0, 0);
      acc[1][ct] = __builtin_amdgcn_mfma_f32_32x32x16_bf16(af1, bfr, acc[1][ct], 0, 0, 0);
    }
  }

  float b3v = b3[r];
  float* sc_base = scores + (((b * 4 + r) * 128 + it * 16) * 128) + jt * 16;
  #pragma unroll
  for (int q = 0; q < 2; ++q) {
    float sp[16];
    #pragma unroll
    for (int g = 0; g < 16; ++g) sp[g] = 0.f;
    #pragma unroll
    for (int ct = 0; ct < 4; ++ct) {
      int e = ct * 32 + m31;
      float w3v = w3[r * 128 + e];
      float b2v = b2[r * 128 + e];
      #pragma unroll
      for (int g = 0; g < 16; ++g)
        sp[g] = fmaf(w3v, fmaxf(acc[q][ct][g] + b2v, 0.f), sp[g]);
    }
    #pragma unroll
    for (int off = 16; off >= 1; off >>= 1)
      #pragma unroll
      for (int g = 0; g < 16; ++g)
        sp[g] += __shfl_xor(sp[g], off, 64);
    if (m31 == 0) {
      int half4 = (l >> 5) << 2;
      #pragma unroll
      for (int g = 0; g < 16; ++g) {
        int p = (w * 2 + q) * 32 + (g & 3) + 8 * (g >> 2) + half4;
        sc_base[(p >> 4) * 128 + (p & 15)] = sp[g] + b3v;
      }
    }
  }
}

__global__ __launch_bounds__(128) void k_softmax_rel(
    const float* __restrict__ scores, const float* __restrict__ f2,
    float* __restrict__ all_rel)
{
  int bid = blockIdx.x;        // 2048 blocks: b(4) x r(4) x i(128)
  int i = bid & 127;
  int r = (bid >> 7) & 3;
  int b = bid >> 9;
  int t = threadIdx.x;
  __shared__ float sraw[128];
  __shared__ float p[128];
  float s = scores[((b * 4 + r) * 128 + i) * 128 + t];
  sraw[t] = s;
  __syncthreads();
  float m = -1e30f;
  for (int j = 0; j < 128; ++j) m = fmaxf(m, sraw[j]);
  float pv = expf(s - m);
  p[t] = pv;
  __syncthreads();
  float sum = 0.f;
  for (int j = 0; j < 128; ++j) sum += p[j];
  float inv = 1.f / sum;
  for (int d = t; d < 256; d += 128) {
    float a = 0.f;
    for (int j = 0; j < 128; ++j)
      a = fmaf(p[j], f2[(b * 128 + j) * 256 + d], a);
    all_rel[(b * 128 + i) * 1024 + r * 256 + d] = a * inv;
  }
}

extern "C" void kernel_launch(void* const* d_in, const int* in_sizes, int n_in,
                              void* d_out, int out_size, void* d_ws, size_t ws_size,
                              hipStream_t stream) {
  const float* f1  = (const float*)d_in[0];
  const float* f2  = (const float*)d_in[1];
  const float* W1  = (const float*)d_in[2];
  const float* b1  = (const float*)d_in[3];
  const float* W2  = (const float*)d_in[4];
  const float* b2  = (const float*)d_in[5];
  const float* w3  = (const float*)d_in[6];
  const float* b3  = (const float*)d_in[7];
  const float* Wa1 = (const float*)d_in[8];
  const float* ba1 = (const float*)d_in[9];
  const float* Wa2 = (const float*)d_in[10];
  const float* ba2 = (const float*)d_in[11];
  float* out = (float*)d_out;
  float* ws = (float*)d_ws;

  float* h1p     = ws;                 // 524288 floats
  float* h2      = ws + 524288;        // 524288
  float* scores  = ws + 1048576;       // 262144
  float* all_rel = ws + 1310720;       // 524288
  float* hidden  = ws + 1835008;       // 262144 (total 8 MB)
  // W2swz aliases `hidden`: dead before gemm1 writes hidden (stream-ordered).
  ushort* W2swz  = (ushort*)(ws + 1835008);

  hipLaunchKernelGGL(k_w2swz, dim3(64), dim3(256), 0, stream, W2, W2swz);
  hipLaunchKernelGGL(k_proj2, dim3(4, 2, 32), dim3(256), 0, stream,
                     f1, f2, W1, b1, h1p, h2);
  hipLaunchKernelGGL(k_scores_mfma, dim3(1024), dim3(256), 0, stream,
                     h1p, h2, W2swz, b2, w3, b3, scores);
  hipLaunchKernelGGL(k_softmax_rel, dim3(2048), dim3(128), 0, stream,
                     scores, f2, all_rel);
  hipLaunchKernelGGL(gemm_tile, dim3(8, 8), dim3(256), 0, stream,
                     all_rel, Wa1, ba1, hidden, 512, 1024, 512, 1);
  hipLaunchKernelGGL(gemm_tile, dim3(4, 8), dim3(256), 0, stream,
                     hidden, Wa2, ba2, out, 512, 512, 256, 0);
}

// Round 4
// 95.976 us; speedup vs baseline: 9.9955x; 1.3832x over previous
//
#include <hip/hip_runtime.h>

// Shapes: B=4, N1=N2=128, D=256, R=4, E=D/2=128
// Pipeline:
//   A: h1p/h2 projections          [fp32 32x64-tile GEMM, 512 blocks]
//   B: scores via bf16 MFMA
//   C: softmax + rel
//   D: final MLP                   [fp32 32x64-tile GEMM, split-K x4 + reduce]

typedef __bf16 bf16x8 __attribute__((ext_vector_type(8)));
typedef float f32x16 __attribute__((ext_vector_type(16)));

#define RS 268

static __device__ __forceinline__ ushort f2b(float f) {
  __bf16 h = (__bf16)f;
  return __builtin_bit_cast(ushort, h);
}

// ---------------- fp32 32x64-tile GEMM core (micro 2x4, KC=32) ----------------
// Computes C tile for rows [rt*32,+32), cols [ct*64,+64), k in [k0, k0+Kblk).
// No bias/act: partial accumulation path. 256 threads.
template<int KBLK>
static __device__ __forceinline__ void gemm32x64_body(
    const float* __restrict__ A, const float* __restrict__ W,
    float* __restrict__ Cout, int K, int N, int rt, int ct, int k0)
{
  int t = threadIdx.x;
  int tm2 = t >> 4;              // 0..15 -> m = tm2*2
  int tn4 = t & 15;              // 0..15 -> n = tn4*4
  int arow = t >> 3;             // 0..31
  int akq = (t & 7) * 4;         // 0,4,..,28
  int bk = t >> 4;               // 0..15
  int bn4 = (t & 15) * 4;
  __shared__ __align__(16) float As[32][33];   // [k][m]
  __shared__ __align__(16) float Bs[32][64];   // [k][n]

  const float* Ab = A + (size_t)(rt * 32 + arow) * K + k0;
  const float* Wb = W + (size_t)k0 * N + ct * 64 + bn4;

  float4 pa = *(const float4*)&Ab[akq];
  float4 pb0 = *(const float4*)&Wb[(size_t)bk * N];
  float4 pb1 = *(const float4*)&Wb[(size_t)(bk + 16) * N];

  float acc[2][4];
  #pragma unroll
  for (int i = 0; i < 2; ++i)
    #pragma unroll
    for (int j = 0; j < 4; ++j) acc[i][j] = 0.f;

  for (int kc = 0; kc < KBLK; kc += 32) {
    __syncthreads();
    As[akq + 0][arow] = pa.x;
    As[akq + 1][arow] = pa.y;
    As[akq + 2][arow] = pa.z;
    As[akq + 3][arow] = pa.w;
    *(float4*)&Bs[bk][bn4] = pb0;
    *(float4*)&Bs[bk + 16][bn4] = pb1;
    __syncthreads();
    if (kc + 32 < KBLK) {
      pa  = *(const float4*)&Ab[kc + 32 + akq];
      pb0 = *(const float4*)&Wb[(size_t)(kc + 32 + bk) * N];
      pb1 = *(const float4*)&Wb[(size_t)(kc + 32 + bk + 16) * N];
    }
    #pragma unroll
    for (int kk = 0; kk < 32; ++kk) {
      float2 a = *(const float2*)&As[kk][tm2 * 2];
      float4 w = *(const float4*)&Bs[kk][tn4 * 4];
      acc[0][0] = fmaf(a.x, w.x, acc[0][0]); acc[0][1] = fmaf(a.x, w.y, acc[0][1]);
      acc[0][2] = fmaf(a.x, w.z, acc[0][2]); acc[0][3] = fmaf(a.x, w.w, acc[0][3]);
      acc[1][0] = fmaf(a.y, w.x, acc[1][0]); acc[1][1] = fmaf(a.y, w.y, acc[1][1]);
      acc[1][2] = fmaf(a.y, w.z, acc[1][2]); acc[1][3] = fmaf(a.y, w.w, acc[1][3]);
    }
  }

  int col = ct * 64 + tn4 * 4;
  #pragma unroll
  for (int qm = 0; qm < 2; ++qm) {
    int row = rt * 32 + tm2 * 2 + qm;
    float4 ov = make_float4(acc[qm][0], acc[qm][1], acc[qm][2], acc[qm][3]);
    *(float4*)&Cout[(size_t)row * N + col] = ov;
  }
}

// Split-K partial GEMM: grid (ct, rt, kp). Writes part[kp][M][N].
template<int KBLK>
__global__ __launch_bounds__(256) void gemm_part(
    const float* __restrict__ A, const float* __restrict__ W,
    float* __restrict__ part, int K, int N, int M)
{
  int kp = blockIdx.z;
  gemm32x64_body<KBLK>(A, W, part + (size_t)kp * M * N, K, N,
                       blockIdx.y, blockIdx.x, kp * KBLK);
}

// Reduce P partials + bias (+relu). One float4 per thread, grid covers M*N/4.
template<int P>
__global__ __launch_bounds__(256) void reduce_bias_act(
    const float* __restrict__ part, const float* __restrict__ bias,
    float* __restrict__ C, int MN, int N, int act)
{
  int idx4 = (blockIdx.x * 256 + threadIdx.x) * 4;
  if (idx4 >= MN) return;
  float4 s = *(const float4*)&part[idx4];
  #pragma unroll
  for (int p = 1; p < P; ++p) {
    float4 v = *(const float4*)&part[(size_t)p * MN + idx4];
    s.x += v.x; s.y += v.y; s.z += v.z; s.w += v.w;
  }
  float4 bv = *(const float4*)&bias[idx4 & (N - 1)];
  s.x += bv.x; s.y += bv.y; s.z += bv.z; s.w += bv.w;
  if (act) {
    s.x = fmaxf(s.x, 0.f); s.y = fmaxf(s.y, 0.f);
    s.z = fmaxf(s.z, 0.f); s.w = fmaxf(s.w, 0.f);
  }
  *(float4*)&C[idx4] = s;
}

// ---------------- projection: grid (ct=4, rt=4, z=32), 32x64 tiles ----------------
__global__ __launch_bounds__(256) void k_proj3(
    const float* __restrict__ f1, const float* __restrict__ f2,
    const float* __restrict__ W1, const float* __restrict__ b1,
    float* __restrict__ h1p, float* __restrict__ h2)
{
  int z = blockIdx.z;
  int half = z >> 4, b = (z >> 2) & 3, r = z & 3;
  int rt = blockIdx.y, ct = blockIdx.x;
  int t = threadIdx.x;
  int tm2 = t >> 4, tn4 = t & 15;
  int arow = t >> 3, akq = (t & 7) * 4;
  int bk = t >> 4, bn4 = (t & 15) * 4;
  __shared__ __align__(16) float As[32][33];
  __shared__ __align__(16) float Bs[32][64];

  const float* A = (half ? f2 : f1) + (size_t)b * 128 * 256;
  const float* W = W1 + (size_t)(r * 512 + half * 256) * 256;
  const float* Ab = A + (rt * 32 + arow) * 256;
  const float* Wb = W + ct * 64 + bn4;

  float4 pa = *(const float4*)&Ab[akq];
  float4 pb0 = *(const float4*)&Wb[bk * 256];
  float4 pb1 = *(const float4*)&Wb[(bk + 16) * 256];

  float acc[2][4];
  #pragma unroll
  for (int i = 0; i < 2; ++i)
    #pragma unroll
    for (int j = 0; j < 4; ++j) acc[i][j] = 0.f;

  for (int kc = 0; kc < 256; kc += 32) {
    __syncthreads();
    As[akq + 0][arow] = pa.x;
    As[akq + 1][arow] = pa.y;
    As[akq + 2][arow] = pa.z;
    As[akq + 3][arow] = pa.w;
    *(float4*)&Bs[bk][bn4] = pb0;
    *(float4*)&Bs[bk + 16][bn4] = pb1;
    __syncthreads();
    if (kc + 32 < 256) {
      pa  = *(const float4*)&Ab[kc + 32 + akq];
      pb0 = *(const float4*)&Wb[(kc + 32 + bk) * 256];
      pb1 = *(const float4*)&Wb[(kc + 32 + bk + 16) * 256];
    }
    #pragma unroll
    for (int kk = 0; kk < 32; ++kk) {
      float2 a = *(const float2*)&As[kk][tm2 * 2];
      float4 w = *(const float4*)&Bs[kk][tn4 * 4];
      acc[0][0] = fmaf(a.x, w.x, acc[0][0]); acc[0][1] = fmaf(a.x, w.y, acc[0][1]);
      acc[0][2] = fmaf(a.x, w.z, acc[0][2]); acc[0][3] = fmaf(a.x, w.w, acc[0][3]);
      acc[1][0] = fmaf(a.y, w.x, acc[1][0]); acc[1][1] = fmaf(a.y, w.y, acc[1][1]);
      acc[1][2] = fmaf(a.y, w.z, acc[1][2]); acc[1][3] = fmaf(a.y, w.w, acc[1][3]);
    }
  }

  int col = ct * 64 + tn4 * 4;
  float4 bv;
  if (half) { bv.x = bv.y = bv.z = bv.w = 0.f; }
  else      { bv = *(const float4*)&b1[r * 256 + col]; }
  float* ho = half ? h2 : h1p;
  #pragma unroll
  for (int qm = 0; qm < 2; ++qm) {
    int row = rt * 32 + tm2 * 2 + qm;
    float4 ov = make_float4(acc[qm][0] + bv.x, acc[qm][1] + bv.y,
                            acc[qm][2] + bv.z, acc[qm][3] + bv.w);
    *(float4*)&ho[((size_t)(b * 4 + r) * 128 + row) * 256 + col] = ov;
  }
}

// ---------------- W2 pre-swizzle (B-fragment order for 32x32x16 bf16) ----------------
__global__ __launch_bounds__(256) void k_w2swz(
    const float* __restrict__ W2, ushort* __restrict__ W2swz)
{
  int bid = blockIdx.x;          // 64 blocks: r(4) x ks(16)
  int r = bid >> 4, ks = bid & 15;
  int t = threadIdx.x;
  int ct = t >> 6, l = t & 63;
  ushort us[8];
  #pragma unroll
  for (int j = 0; j < 8; ++j) {
    int d = ks * 16 + ((j >> 2) * 8) + ((l >> 5) * 4) + (j & 3);
    int e = ct * 32 + (l & 31);
    us[j] = f2b(W2[(r * 256 + d) * 128 + e]);
  }
  uint4 pk;
  pk.x = (uint)us[0] | ((uint)us[1] << 16);
  pk.y = (uint)us[2] | ((uint)us[3] << 16);
  pk.z = (uint)us[4] | ((uint)us[5] << 16);
  pk.w = (uint)us[6] | ((uint)us[7] << 16);
  *(uint4*)&W2swz[(((r * 16 + ks) * 4 + ct) * 64 + l) * 8] = pk;
}

// ---------------- MFMA scores kernel ----------------
__global__ __launch_bounds__(256, 2) void k_scores_mfma(
    const float* __restrict__ h1p, const float* __restrict__ h2,
    const ushort* __restrict__ W2swz, const float* __restrict__ b2,
    const float* __restrict__ w3, const float* __restrict__ b3,
    float* __restrict__ scores)
{
  int bid = blockIdx.x;        // 1024 blocks: b(4) x r(4) x it(8) x jt(8)
  int jt = bid & 7;
  int it = (bid >> 3) & 7;
  int r  = (bid >> 6) & 3;
  int b  = bid >> 8;
  int t = threadIdx.x, w = t >> 6, l = t & 63;
  __shared__ float h1s[16][RS];
  __shared__ float h2s[16][RS];
  __shared__ __align__(16) ushort A_lds[2][8 * 64 * 8];

  const float* h1g = h1p + ((b * 4 + r) * 128 + it * 16) * 256;
  const float* h2g = h2  + ((b * 4 + r) * 128 + jt * 16) * 256;
  for (int idx = t; idx < 1024; idx += 256) {
    int ii = idx >> 6, d4 = (idx & 63) << 2;
    *(float4*)&h1s[ii][d4] = *(const float4*)&h1g[ii * 256 + d4];
    *(float4*)&h2s[ii][d4] = *(const float4*)&h2g[ii * 256 + d4];
  }

  f32x16 acc[2][4];
  #pragma unroll
  for (int q = 0; q < 2; ++q)
    #pragma unroll
    for (int c = 0; c < 4; ++c)
      #pragma unroll
      for (int e = 0; e < 16; ++e) acc[q][c][e] = 0.f;

  const ushort* bptr = W2swz + r * (16 * 4 * 64 * 8);
  int kb_lane = (l >> 5) << 2;
  int m31 = l & 31;
  int jrow = l & 15;

  __syncthreads();

  for (int ks = 0; ks < 16; ++ks) {
    int buf = ks & 1;
    #pragma unroll
    for (int q = 0; q < 2; ++q) {
      int rt = w * 2 + q;
      int p = rt * 32 + m31;
      int irow = p >> 4;
      int kb0 = ks * 16 + kb_lane;
      float4 xa = *(const float4*)&h1s[irow][kb0];
      float4 xb = *(const float4*)&h1s[irow][kb0 + 8];
      float4 ya = *(const float4*)&h2s[jrow][kb0];
      float4 yb = *(const float4*)&h2s[jrow][kb0 + 8];
      float v0 = fmaxf(xa.x + ya.x, 0.f), v1 = fmaxf(xa.y + ya.y, 0.f);
      float v2 = fmaxf(xa.z + ya.z, 0.f), v3 = fmaxf(xa.w + ya.w, 0.f);
      float v4 = fmaxf(xb.x + yb.x, 0.f), v5 = fmaxf(xb.y + yb.y, 0.f);
      float v6 = fmaxf(xb.z + yb.z, 0.f), v7 = fmaxf(xb.w + yb.w, 0.f);
      uint4 pk;
      pk.x = (uint)f2b(v0) | ((uint)f2b(v1) << 16);
      pk.y = (uint)f2b(v2) | ((uint)f2b(v3) << 16);
      pk.z = (uint)f2b(v4) | ((uint)f2b(v5) << 16);
      pk.w = (uint)f2b(v6) | ((uint)f2b(v7) << 16);
      *(uint4*)&A_lds[buf][(rt * 64 + l) * 8] = pk;
    }
    __syncthreads();
    uint4 a0r = *(const uint4*)&A_lds[buf][((w * 2 + 0) * 64 + l) * 8];
    uint4 a1r = *(const uint4*)&A_lds[buf][((w * 2 + 1) * 64 + l) * 8];
    bf16x8 af0 = __builtin_bit_cast(bf16x8, a0r);
    bf16x8 af1 = __builtin_bit_cast(bf16x8, a1r);
    #pragma unroll
    for (int ct = 0; ct < 4; ++ct) {
      uint4 braw = *(const uint4*)&bptr[((ks * 4 + ct) * 64 + l) * 8];
      bf16x8 bfr = __builtin_bit_cast(bf16x8, braw);
      acc[0][ct] = __builtin_amdgcn_mfma_f32_32x32x16_bf16(af0, bfr, acc[0][ct], 0, 0, 0);
      acc[1][ct] = __builtin_amdgcn_mfma_f32_32x32x16_bf16(af1, bfr, acc[1][ct], 0, 0, 0);
    }
  }

  float b3v = b3[r];
  float* sc_base = scores + (((b * 4 + r) * 128 + it * 16) * 128) + jt * 16;
  #pragma unroll
  for (int q = 0; q < 2; ++q) {
    float sp[16];
    #pragma unroll
    for (int g = 0; g < 16; ++g) sp[g] = 0.f;
    #pragma unroll
    for (int ct = 0; ct < 4; ++ct) {
      int e = ct * 32 + m31;
      float w3v = w3[r * 128 + e];
      float b2v = b2[r * 128 + e];
      #pragma unroll
      for (int g = 0; g < 16; ++g)
        sp[g] = fmaf(w3v, fmaxf(acc[q][ct][g] + b2v, 0.f), sp[g]);
    }
    #pragma unroll
    for (int off = 16; off >= 1; off >>= 1)
      #pragma unroll
      for (int g = 0; g < 16; ++g)
        sp[g] += __shfl_xor(sp[g], off, 64);
    if (m31 == 0) {
      int half4 = (l >> 5) << 2;
      #pragma unroll
      for (int g = 0; g < 16; ++g) {
        int p = (w * 2 + q) * 32 + (g & 3) + 8 * (g >> 2) + half4;
        sc_base[(p >> 4) * 128 + (p & 15)] = sp[g] + b3v;
      }
    }
  }
}

__global__ __launch_bounds__(128) void k_softmax_rel(
    const float* __restrict__ scores, const float* __restrict__ f2,
    float* __restrict__ all_rel)
{
  int bid = blockIdx.x;        // 2048 blocks: b(4) x r(4) x i(128)
  int i = bid & 127;
  int r = (bid >> 7) & 3;
  int b = bid >> 9;
  int t = threadIdx.x;
  __shared__ float sraw[128];
  __shared__ float p[128];
  float s = scores[((b * 4 + r) * 128 + i) * 128 + t];
  sraw[t] = s;
  __syncthreads();
  float m = -1e30f;
  for (int j = 0; j < 128; ++j) m = fmaxf(m, sraw[j]);
  float pv = expf(s - m);
  p[t] = pv;
  __syncthreads();
  float sum = 0.f;
  for (int j = 0; j < 128; ++j) sum += p[j];
  float inv = 1.f / sum;
  for (int d = t; d < 256; d += 128) {
    float a = 0.f;
    for (int j = 0; j < 128; ++j)
      a = fmaf(p[j], f2[(b * 128 + j) * 256 + d], a);
    all_rel[(b * 128 + i) * 1024 + r * 256 + d] = a * inv;
  }
}

extern "C" void kernel_launch(void* const* d_in, const int* in_sizes, int n_in,
                              void* d_out, int out_size, void* d_ws, size_t ws_size,
                              hipStream_t stream) {
  const float* f1  = (const float*)d_in[0];
  const float* f2  = (const float*)d_in[1];
  const float* W1  = (const float*)d_in[2];
  const float* b1  = (const float*)d_in[3];
  const float* W2  = (const float*)d_in[4];
  const float* b2  = (const float*)d_in[5];
  const float* w3  = (const float*)d_in[6];
  const float* b3  = (const float*)d_in[7];
  const float* Wa1 = (const float*)d_in[8];
  const float* ba1 = (const float*)d_in[9];
  const float* Wa2 = (const float*)d_in[10];
  const float* ba2 = (const float*)d_in[11];
  float* out = (float*)d_out;
  float* ws = (float*)d_ws;

  float* h1p     = ws;                 // 524288 floats (2MB)
  float* h2      = ws + 524288;        // 524288
  float* scores  = ws + 1048576;       // 262144 (1MB)
  float* all_rel = ws + 1310720;       // 524288 (2MB)
  float* hidden  = ws + 1835008;       // 262144 (1MB); W2swz aliases here (dead by then)
  ushort* W2swz  = (ushort*)(ws + 1835008);
  // Split-K partials alias dead regions (stream-ordered):
  float* p1 = ws;                      // 4x 512x512 = 1048576 floats = h1p+h2 (dead after scores)
  float* p2 = ws + 1310720;            // 4x 512x256 = 524288 floats = all_rel (dead after gemm1)

  hipLaunchKernelGGL(k_w2swz, dim3(64), dim3(256), 0, stream, W2, W2swz);
  hipLaunchKernelGGL(k_proj3, dim3(4, 4, 32), dim3(256), 0, stream,
                     f1, f2, W1, b1, h1p, h2);
  hipLaunchKernelGGL(k_scores_mfma, dim3(1024), dim3(256), 0, stream,
                     h1p, h2, W2swz, b2, w3, b3, scores);
  hipLaunchKernelGGL(k_softmax_rel, dim3(2048), dim3(128), 0, stream,
                     scores, f2, all_rel);
  // gemm1: hidden = relu(all_rel[512,1024] @ Wa1[1024,512] + ba1)
  hipLaunchKernelGGL((gemm_part<256>), dim3(8, 16, 4), dim3(256), 0, stream,
                     all_rel, Wa1, p1, 1024, 512, 512);
  hipLaunchKernelGGL((reduce_bias_act<4>), dim3(256), dim3(256), 0, stream,
                     p1, ba1, hidden, 512 * 512, 512, 1);
  // gemm2: out = hidden[512,512] @ Wa2[512,256] + ba2
  hipLaunchKernelGGL((gemm_part<128>), dim3(4, 16, 4), dim3(256), 0, stream,
                     hidden, Wa2, p2, 512, 256, 512);
  hipLaunchKernelGGL((reduce_bias_act<4>), dim3(128), dim3(256), 0, stream,
                     p2, ba2, out, 512 * 256, 256, 0);
}